// Round 1
// baseline (1050.558 us; speedup 1.0000x reference)
//
#include <hip/hip_runtime.h>
#include <stdint.h>
#include <stddef.h>

typedef __bf16 bf16;
typedef __bf16 bf16x8 __attribute__((ext_vector_type(8)));
typedef __bf16 bf16x4 __attribute__((ext_vector_type(4)));
typedef float  f32x4  __attribute__((ext_vector_type(4)));

#define NB      4096        // batch
#define NF      4096        // features (= K = N for all GEMMs)
#define NCODES  (NB * NF / 64)   // 262144
#define NEMB    512
#define EDIM    64

// ---------------------------------------------------------------- helpers
__device__ __forceinline__ void gld_lds16(const void* g, void* l) {
  __builtin_amdgcn_global_load_lds(
      (const __attribute__((address_space(1))) void*)g,
      (__attribute__((address_space(3))) void*)l, 16, 0, 0);
}

// ---------------------------------------------------------------- f32 -> bf16 convert
__global__ void cvt_f32_bf16(const float* __restrict__ in, bf16* __restrict__ out, int n8) {
  int idx = blockIdx.x * blockDim.x + threadIdx.x;
  int stride = gridDim.x * blockDim.x;
  for (int i = idx; i < n8; i += stride) {
    const float4* p = (const float4*)(in + (size_t)i * 8);
    float4 a = p[0], b = p[1];
    bf16x8 o;
    o[0] = (bf16)a.x; o[1] = (bf16)a.y; o[2] = (bf16)a.z; o[3] = (bf16)a.w;
    o[4] = (bf16)b.x; o[5] = (bf16)b.y; o[6] = (bf16)b.z; o[7] = (bf16)b.w;
    *(bf16x8*)(out + (size_t)i * 8) = o;
  }
}

// ---------------------------------------------------------------- codebook prep: bf16 copy + row norms
__global__ void cbprep(const float* __restrict__ cb, bf16* __restrict__ cbbf,
                       float* __restrict__ cbnorm) {
  int r = blockIdx.x * blockDim.x + threadIdx.x;
  if (r < NEMB) {
    float s = 0.f;
    for (int d = 0; d < EDIM; ++d) {
      float v = cb[r * EDIM + d];
      s += v * v;
      cbbf[r * EDIM + d] = (bf16)v;
    }
    cbnorm[r] = s;
  }
}

// ---------------------------------------------------------------- GEMM: C = act(A @ W^T + bias)
// A: [M=4096, K=4096] bf16 row-major, W: [N=4096, K=4096] bf16 row-major.
// m97 structure: 128x128 tile, BK=64, 4 waves (2x2), 4x4 16x16x32 frags/wave.
// OUTMODE: 0 -> f32 out, 1 -> bf16 out.  RELU: 0/1.
template<int OUTMODE, int RELU>
__global__ __launch_bounds__(256, 2)
void gemm_bt(const bf16* __restrict__ A, const bf16* __restrict__ W,
             const float* __restrict__ bias,
             float* __restrict__ outF, bf16* __restrict__ outB) {
  constexpr int K = 4096, N = 4096;
  __shared__ bf16 As[128 * 64];
  __shared__ bf16 Bs[128 * 64];
  const int tid  = threadIdx.x;
  const int wave = tid >> 6;
  const int lane = tid & 63;
  const int l15  = lane & 15;
  const int lg   = lane >> 4;
  const int brow = blockIdx.y * 128;
  const int bcol = blockIdx.x * 128;
  const int wr   = (wave >> 1) * 64;   // wave row offset in tile
  const int wc   = (wave & 1) * 64;    // wave col offset in tile

  f32x4 acc[4][4];
#pragma unroll
  for (int i = 0; i < 4; ++i)
#pragma unroll
    for (int j = 0; j < 4; ++j)
      acc[i][j] = f32x4{0.f, 0.f, 0.f, 0.f};

  for (int k0 = 0; k0 < K; k0 += 64) {
    // stage A-tile and W-tile: 1024 16B chunks each, 4+4 per thread
#pragma unroll
    for (int i = 0; i < 4; ++i) {
      int c   = i * 256 + tid;
      int row = c >> 3;          // [0,128)
      int k8  = (c & 7) * 8;     // [0,64) in steps of 8
      gld_lds16(A + (size_t)(brow + row) * K + k0 + k8, As + c * 8);
      gld_lds16(W + (size_t)(bcol + row) * K + k0 + k8, Bs + c * 8);
    }
    __syncthreads();   // drains vmcnt -> LDS ready
#pragma unroll
    for (int kk = 0; kk < 64; kk += 32) {
      bf16x8 af[4], bw[4];
#pragma unroll
      for (int i = 0; i < 4; ++i)
        af[i] = *(const bf16x8*)(As + (wr + i * 16 + l15) * 64 + kk + lg * 8);
#pragma unroll
      for (int j = 0; j < 4; ++j)
        bw[j] = *(const bf16x8*)(Bs + (wc + j * 16 + l15) * 64 + kk + lg * 8);
#pragma unroll
      for (int i = 0; i < 4; ++i)
#pragma unroll
        for (int j = 0; j < 4; ++j)
          acc[i][j] = __builtin_amdgcn_mfma_f32_16x16x32_bf16(af[i], bw[j], acc[i][j], 0, 0, 0);
    }
    __syncthreads();   // protect LDS before next stage
  }

  // epilogue: C/D layout col = lane&15, row = (lane>>4)*4 + reg  [m89]
#pragma unroll
  for (int i = 0; i < 4; ++i) {
#pragma unroll
    for (int j = 0; j < 4; ++j) {
      int col = bcol + wc + j * 16 + l15;
      float bv = bias[col];
#pragma unroll
      for (int r = 0; r < 4; ++r) {
        int row = brow + wr + i * 16 + lg * 4 + r;
        float v = acc[i][j][r] + bv;
        if (RELU) v = fmaxf(v, 0.f);
        size_t o = (size_t)row * N + col;
        if (OUTMODE == 0) outF[o] = v;
        else              outB[o] = (bf16)v;
      }
    }
  }
}

// ---------------------------------------------------------------- VQ: argmin + quantize + losses
// latent: [NCODES][64] f32. Per block: 4 waves x 16 rows = 64 rows.
// Wave computes scores vs all 512 codebook rows via 16x16x32 MFMA, K=64.
__global__ __launch_bounds__(256, 2)
void vq_kernel(const float* __restrict__ latent,
               const float* __restrict__ cb, const bf16* __restrict__ cbbf,
               const float* __restrict__ cbnorm,
               bf16* __restrict__ qbf, unsigned int* __restrict__ hist,
               float* __restrict__ sse_out) {
  __shared__ unsigned lhist[NEMB];
  const int tid = threadIdx.x;
  lhist[tid] = 0; lhist[tid + 256] = 0;
  __syncthreads();

  const int wave = tid >> 6, lane = tid & 63;
  const int l15 = lane & 15, lg = lane >> 4;
  const int rowbase = blockIdx.x * 64 + wave * 16;

  // A-frags (code rows as bf16, built from f32 latent): lane holds row l15, k = lg*8 + j (+32)
  const float* ap = latent + (size_t)(rowbase + l15) * EDIM + lg * 8;
  float4 af0 = *(const float4*)(ap);
  float4 af1 = *(const float4*)(ap + 4);
  float4 af2 = *(const float4*)(ap + 32);
  float4 af3 = *(const float4*)(ap + 36);
  bf16x8 a0, a1;
  a0[0]=(bf16)af0.x; a0[1]=(bf16)af0.y; a0[2]=(bf16)af0.z; a0[3]=(bf16)af0.w;
  a0[4]=(bf16)af1.x; a0[5]=(bf16)af1.y; a0[6]=(bf16)af1.z; a0[7]=(bf16)af1.w;
  a1[0]=(bf16)af2.x; a1[1]=(bf16)af2.y; a1[2]=(bf16)af2.z; a1[3]=(bf16)af2.w;
  a1[4]=(bf16)af3.x; a1[5]=(bf16)af3.y; a1[6]=(bf16)af3.z; a1[7]=(bf16)af3.w;

  float best[4] = {1e30f, 1e30f, 1e30f, 1e30f};
  int   bidx[4] = {0, 0, 0, 0};

  for (int ct = 0; ct < 32; ++ct) {
    const bf16* bp = cbbf + (size_t)(ct * 16 + l15) * EDIM + lg * 8;
    bf16x8 b0 = *(const bf16x8*)bp;
    bf16x8 b1 = *(const bf16x8*)(bp + 32);
    f32x4 accv = f32x4{0.f, 0.f, 0.f, 0.f};
    accv = __builtin_amdgcn_mfma_f32_16x16x32_bf16(a0, b0, accv, 0, 0, 0);
    accv = __builtin_amdgcn_mfma_f32_16x16x32_bf16(a1, b1, accv, 0, 0, 0);
    int c = ct * 16 + l15;
    float cn = cbnorm[c];
#pragma unroll
    for (int r = 0; r < 4; ++r) {
      float s = cn - 2.0f * accv[r];   // + ||code||^2 (row const) dropped
      if (s < best[r] || (s == best[r] && c < bidx[r])) { best[r] = s; bidx[r] = c; }
    }
  }
  // min+argmin across the 16 lanes of each column group (first-index tie-break)
#pragma unroll
  for (int m = 1; m < 16; m <<= 1) {
#pragma unroll
    for (int r = 0; r < 4; ++r) {
      float ov = __shfl_xor(best[r], m);
      int   oi = __shfl_xor(bidx[r], m);
      if (ov < best[r] || (ov == best[r] && oi < bidx[r])) { best[r] = ov; bidx[r] = oi; }
    }
  }

  float sse = 0.f;
#pragma unroll
  for (int r = 0; r < 4; ++r) {
    int row = rowbase + lg * 4 + r;
    int idx = bidx[r];
    float4 e  = *(const float4*)(cb + (size_t)idx * EDIM + l15 * 4);
    float4 cv = *(const float4*)(latent + (size_t)row * EDIM + l15 * 4);
    float d0 = e.x - cv.x, d1 = e.y - cv.y, d2 = e.z - cv.z, d3 = e.w - cv.w;
    sse += d0 * d0 + d1 * d1 + d2 * d2 + d3 * d3;
    bf16x4 q;
    q[0] = (bf16)e.x; q[1] = (bf16)e.y; q[2] = (bf16)e.z; q[3] = (bf16)e.w;
    *(bf16x4*)(qbf + (size_t)row * EDIM + l15 * 4) = q;
    if (l15 == 0) atomicAdd(&lhist[idx], 1u);
  }
  // wave-reduce SSE, one atomic per wave
#pragma unroll
  for (int m = 1; m < 64; m <<= 1) sse += __shfl_xor(sse, m);
  if (lane == 0) atomicAdd(sse_out, sse);

  __syncthreads();
  unsigned v0 = lhist[tid], v1 = lhist[tid + 256];
  if (v0) atomicAdd(hist + tid, v0);
  if (v1) atomicAdd(hist + tid + 256, v1);
}

// ---------------------------------------------------------------- finalize: vq_loss + perplexity
__global__ void finalize_k(const unsigned* __restrict__ hist, const float* __restrict__ sse,
                           float* __restrict__ out_tail) {
  __shared__ float red[512];
  int t = threadIdx.x;
  float p = (float)hist[t] * (1.0f / (float)NCODES);
  red[t] = p * logf(p + 1e-10f);
  __syncthreads();
  for (int s = 256; s > 0; s >>= 1) {
    if (t < s) red[t] += red[t + s];
    __syncthreads();
  }
  if (t == 0) {
    out_tail[0] = 1.25f * sse[0] * (1.0f / ((float)NCODES * (float)EDIM));  // q + 0.25*e latent loss
    out_tail[1] = expf(-red[0]);                                            // perplexity
  }
}

// ---------------------------------------------------------------- launch
extern "C" void kernel_launch(void* const* d_in, const int* in_sizes, int n_in,
                              void* d_out, int out_size, void* d_ws, size_t ws_size,
                              hipStream_t stream) {
  const float* x  = (const float*)d_in[0];
  const float* W1 = (const float*)d_in[1];
  const float* b1 = (const float*)d_in[2];
  const float* W2 = (const float*)d_in[3];
  const float* b2 = (const float*)d_in[4];
  const float* W3 = (const float*)d_in[5];
  const float* b3 = (const float*)d_in[6];
  const float* W4 = (const float*)d_in[7];
  const float* b4 = (const float*)d_in[8];
  const float* cb = (const float*)d_in[9];
  float* out = (float*)d_out;

  char* ws = (char*)d_ws;
  float*    sse    = (float*)(ws + 0);        // 4 B
  unsigned* hist   = (unsigned*)(ws + 1024);  // 2 KB
  float*    cbnorm = (float*)(ws + 4096);     // 2 KB
  bf16*     cbbf   = (bf16*)(ws + 8192);      // 64 KB
  size_t off = 131072;
  bf16* xbf  = (bf16*)(ws + off);  off += (size_t)NB * NF * 2;   // 33.5 MB
  bf16* wbuf = (bf16*)(ws + off);  off += (size_t)NB * NF * 2;   // 33.5 MB (reused for W1..W4)
  bf16* hbf  = (bf16*)(ws + off);  off += (size_t)NB * NF * 2;   // 33.5 MB
  float* latent = (float*)(ws + off); off += (size_t)NB * NF * 4; // 67 MB
  bf16* qbf  = xbf;   // alias: x dead after GEMM1
  bf16* h2bf = hbf;   // alias: h dead after GEMM2

  hipMemsetAsync(ws, 0, 3072, stream);  // sse + hist

  const int n8 = NB * NF / 8;
  cvt_f32_bf16<<<dim3(2048), dim3(256), 0, stream>>>(x,  xbf,  n8);
  cvt_f32_bf16<<<dim3(2048), dim3(256), 0, stream>>>(W1, wbuf, n8);
  cbprep<<<dim3(2), dim3(256), 0, stream>>>(cb, cbbf, cbnorm);

  dim3 ggrid(32, 32), gblock(256);
  // h = relu(x @ W1^T + b1) -> bf16
  gemm_bt<1, 1><<<ggrid, gblock, 0, stream>>>(xbf, wbuf, b1, (float*)nullptr, hbf);
  cvt_f32_bf16<<<dim3(2048), dim3(256), 0, stream>>>(W2, wbuf, n8);
  // latent = h @ W2^T + b2 -> f32
  gemm_bt<0, 0><<<ggrid, gblock, 0, stream>>>(hbf, wbuf, b2, latent, (bf16*)nullptr);
  // VQ: argmin, quantized (bf16), histogram, SSE
  vq_kernel<<<dim3(NCODES / 64), dim3(256), 0, stream>>>(latent, cb, cbbf, cbnorm, qbf, hist, sse);
  cvt_f32_bf16<<<dim3(2048), dim3(256), 0, stream>>>(W3, wbuf, n8);
  // h2 = relu(q @ W3^T + b3) -> bf16
  gemm_bt<1, 1><<<ggrid, gblock, 0, stream>>>(qbf, wbuf, b3, (float*)nullptr, h2bf);
  cvt_f32_bf16<<<dim3(2048), dim3(256), 0, stream>>>(W4, wbuf, n8);
  // recons = h2 @ W4^T + b4 -> f32 (d_out)
  gemm_bt<0, 0><<<ggrid, gblock, 0, stream>>>(h2bf, wbuf, b4, out, (bf16*)nullptr);

  finalize_k<<<dim3(1), dim3(512), 0, stream>>>(hist, sse, out + (size_t)NB * NF);
}

// Round 2
// 846.690 us; speedup vs baseline: 1.2408x; 1.2408x over previous
//
#include <hip/hip_runtime.h>
#include <stdint.h>
#include <stddef.h>

typedef __bf16 bf16;
typedef __bf16 bf16x8 __attribute__((ext_vector_type(8)));
typedef __bf16 bf16x4 __attribute__((ext_vector_type(4)));
typedef float  f32x4  __attribute__((ext_vector_type(4)));

#define NB      4096        // batch
#define NF      4096        // features (= K = N for all GEMMs)
#define NCODES  (NB * NF / 64)   // 262144
#define NEMB    512
#define EDIM    64

// ---------------------------------------------------------------- helpers
__device__ __forceinline__ void gld_lds16(const void* g, void* l) {
  __builtin_amdgcn_global_load_lds(
      (const __attribute__((address_space(1))) void*)g,
      (__attribute__((address_space(3))) void*)l, 16, 0, 0);
}

// ---------------------------------------------------------------- f32 -> bf16 convert
__global__ void cvt_f32_bf16(const float* __restrict__ in, bf16* __restrict__ out, int n8) {
  int idx = blockIdx.x * blockDim.x + threadIdx.x;
  int stride = gridDim.x * blockDim.x;
  for (int i = idx; i < n8; i += stride) {
    const float4* p = (const float4*)(in + (size_t)i * 8);
    float4 a = p[0], b = p[1];
    bf16x8 o;
    o[0] = (bf16)a.x; o[1] = (bf16)a.y; o[2] = (bf16)a.z; o[3] = (bf16)a.w;
    o[4] = (bf16)b.x; o[5] = (bf16)b.y; o[6] = (bf16)b.z; o[7] = (bf16)b.w;
    *(bf16x8*)(out + (size_t)i * 8) = o;
  }
}

// ---------------------------------------------------------------- codebook prep: bf16 copy + row norms
__global__ void cbprep(const float* __restrict__ cb, bf16* __restrict__ cbbf,
                       float* __restrict__ cbnorm) {
  int r = blockIdx.x * blockDim.x + threadIdx.x;
  if (r < NEMB) {
    float s = 0.f;
    for (int d = 0; d < EDIM; ++d) {
      float v = cb[r * EDIM + d];
      s += v * v;
      cbbf[r * EDIM + d] = (bf16)v;
    }
    cbnorm[r] = s;
  }
}

// ---------------------------------------------------------------- GEMM: C = act(A @ W^T + bias)
// A: [M=4096, K=4096] bf16 row-major, W: [N=4096, K=4096] bf16 row-major.
// m97 structure: 128x128 tile, BK=64, 4 waves (2x2), 4x4 16x16x32 frags/wave.
// OUTMODE: 0 -> f32 out, 1 -> bf16 out.  RELU: 0/1.
template<int OUTMODE, int RELU>
__global__ __launch_bounds__(256, 2)
void gemm_bt(const bf16* __restrict__ A, const bf16* __restrict__ W,
             const float* __restrict__ bias,
             float* __restrict__ outF, bf16* __restrict__ outB) {
  constexpr int K = 4096, N = 4096;
  __shared__ bf16 As[128 * 64];
  __shared__ bf16 Bs[128 * 64];
  const int tid  = threadIdx.x;
  const int wave = tid >> 6;
  const int lane = tid & 63;
  const int l15  = lane & 15;
  const int lg   = lane >> 4;
  const int brow = blockIdx.y * 128;
  const int bcol = blockIdx.x * 128;
  const int wr   = (wave >> 1) * 64;   // wave row offset in tile
  const int wc   = (wave & 1) * 64;    // wave col offset in tile

  f32x4 acc[4][4];
#pragma unroll
  for (int i = 0; i < 4; ++i)
#pragma unroll
    for (int j = 0; j < 4; ++j)
      acc[i][j] = f32x4{0.f, 0.f, 0.f, 0.f};

  for (int k0 = 0; k0 < K; k0 += 64) {
    // stage A-tile and W-tile: 1024 16B chunks each, 4+4 per thread
#pragma unroll
    for (int i = 0; i < 4; ++i) {
      int c   = i * 256 + tid;
      int row = c >> 3;          // [0,128)
      int k8  = (c & 7) * 8;     // [0,64) in steps of 8
      gld_lds16(A + (size_t)(brow + row) * K + k0 + k8, As + c * 8);
      gld_lds16(W + (size_t)(bcol + row) * K + k0 + k8, Bs + c * 8);
    }
    __syncthreads();   // drains vmcnt -> LDS ready
#pragma unroll
    for (int kk = 0; kk < 64; kk += 32) {
      bf16x8 af[4], bw[4];
#pragma unroll
      for (int i = 0; i < 4; ++i)
        af[i] = *(const bf16x8*)(As + (wr + i * 16 + l15) * 64 + kk + lg * 8);
#pragma unroll
      for (int j = 0; j < 4; ++j)
        bw[j] = *(const bf16x8*)(Bs + (wc + j * 16 + l15) * 64 + kk + lg * 8);
#pragma unroll
      for (int i = 0; i < 4; ++i)
#pragma unroll
        for (int j = 0; j < 4; ++j)
          acc[i][j] = __builtin_amdgcn_mfma_f32_16x16x32_bf16(af[i], bw[j], acc[i][j], 0, 0, 0);
    }
    __syncthreads();   // protect LDS before next stage
  }

  // epilogue: C/D layout col = lane&15, row = (lane>>4)*4 + reg  [m89]
#pragma unroll
  for (int i = 0; i < 4; ++i) {
#pragma unroll
    for (int j = 0; j < 4; ++j) {
      int col = bcol + wc + j * 16 + l15;
      float bv = bias[col];
#pragma unroll
      for (int r = 0; r < 4; ++r) {
        int row = brow + wr + i * 16 + lg * 4 + r;
        float v = acc[i][j][r] + bv;
        if (RELU) v = fmaxf(v, 0.f);
        size_t o = (size_t)row * N + col;
        if (OUTMODE == 0) outF[o] = v;
        else              outB[o] = (bf16)v;
      }
    }
  }
}

// ---------------------------------------------------------------- VQ v2: LDS codebook, 4-group ILP,
// packed-key argmin reduce, 1 SSE atomic/block, per-block hist flush.
// Grid: 512 blocks x 512 threads (8 waves). Each wave owns 64 rows (4 frag groups of 16).
__global__ __launch_bounds__(512, 2)
void vq_kernel(const float* __restrict__ latent,
               const float* __restrict__ cb, const bf16* __restrict__ cbbf_g,
               const float* __restrict__ cbnorm_g,
               bf16* __restrict__ qbf, unsigned int* __restrict__ hist,
               float* __restrict__ sse_out) {
  __shared__ bf16     cbl[NEMB * EDIM];   // 64 KB, XOR-swizzled at 16B granularity
  __shared__ float    cnl[NEMB];          // 2 KB
  __shared__ unsigned lhist[NEMB];        // 2 KB
  __shared__ float    swse[8];

  const int tid = threadIdx.x;
  // stage codebook (swizzled: 16B-unit u -> u ^ ((u>>3)&7)) + norms + hist init
  lhist[tid] = 0;
  cnl[tid] = cbnorm_g[tid];
  {
    const uint4* src = (const uint4*)cbbf_g;   // 4096 16B units
    uint4* dst = (uint4*)cbl;
#pragma unroll
    for (int i = 0; i < 8; ++i) {
      int u = tid + i * 512;
      dst[u ^ ((u >> 3) & 7)] = src[u];
    }
  }
  __syncthreads();

  const int wave = tid >> 6, lane = tid & 63;
  const int l15 = lane & 15, lg = lane >> 4;
  const int base = blockIdx.x * 512 + wave * 64;

  // A-frags: 4 groups of 16 rows. lane holds row (g*16+l15), dims lg*8..+8 and 32+lg*8..+8
  bf16x8 a0[4], a1[4];
#pragma unroll
  for (int g = 0; g < 4; ++g) {
    const float* ap = latent + (size_t)(base + g * 16 + l15) * EDIM + lg * 8;
    float4 f0 = *(const float4*)(ap);
    float4 f1 = *(const float4*)(ap + 4);
    float4 f2 = *(const float4*)(ap + 32);
    float4 f3 = *(const float4*)(ap + 36);
    bf16x8 t0, t1;
    t0[0]=(bf16)f0.x; t0[1]=(bf16)f0.y; t0[2]=(bf16)f0.z; t0[3]=(bf16)f0.w;
    t0[4]=(bf16)f1.x; t0[5]=(bf16)f1.y; t0[6]=(bf16)f1.z; t0[7]=(bf16)f1.w;
    t1[0]=(bf16)f2.x; t1[1]=(bf16)f2.y; t1[2]=(bf16)f2.z; t1[3]=(bf16)f2.w;
    t1[4]=(bf16)f3.x; t1[5]=(bf16)f3.y; t1[6]=(bf16)f3.z; t1[7]=(bf16)f3.w;
    a0[g] = t0; a1[g] = t1;
  }

  float best[4][4];
  int   bidx[4][4];
#pragma unroll
  for (int g = 0; g < 4; ++g)
#pragma unroll
    for (int r = 0; r < 4; ++r) { best[g][r] = 1e30f; bidx[g][r] = 0; }

  for (int ct = 0; ct < 32; ++ct) {
    const int row = ct * 16 + l15;
    const int u0 = ((row << 3) + lg) ^ (row & 7);   // swizzled 16B unit
    bf16x8 b0 = *(const bf16x8*)(cbl + u0 * 8);
    bf16x8 b1 = *(const bf16x8*)(cbl + (u0 ^ 4) * 8);
    float cn = cnl[row];
    int   c  = row;
#pragma unroll
    for (int g = 0; g < 4; ++g) {
      f32x4 acc = f32x4{0.f, 0.f, 0.f, 0.f};
      acc = __builtin_amdgcn_mfma_f32_16x16x32_bf16(a0[g], b0, acc, 0, 0, 0);
      acc = __builtin_amdgcn_mfma_f32_16x16x32_bf16(a1[g], b1, acc, 0, 0, 0);
#pragma unroll
      for (int r = 0; r < 4; ++r) {
        float s = fmaf(-2.0f, acc[r], cn);   // + ||code||^2 (row-const) dropped
        if (s < best[g][r]) { best[g][r] = s; bidx[g][r] = c; }  // strict < keeps first
      }
    }
  }

  // cross-lane argmin: pack ordered-float (high 23 bits) | index (9 bits), min-reduce over l15
  float sse = 0.f;
#pragma unroll
  for (int g = 0; g < 4; ++g) {
#pragma unroll
    for (int r = 0; r < 4; ++r) {
      uint32_t bits = __float_as_uint(best[g][r]);
      uint32_t u = bits ^ ((uint32_t)((int32_t)bits >> 31) | 0x80000000u);
      uint32_t key = (u & 0xFFFFFE00u) | (uint32_t)bidx[g][r];
#pragma unroll
      for (int m = 1; m < 16; m <<= 1) {
        uint32_t o = __shfl_xor(key, m);
        key = (o < key) ? o : key;
      }
      int idx = (int)(key & 511u);
      // row for this (lg, r): quantize + SSE + hist
      int rowg = base + g * 16 + lg * 4 + r;
      float4 cv = *(const float4*)(latent + (size_t)rowg * EDIM + l15 * 4);
      float4 e  = *(const float4*)(cb + (size_t)idx * EDIM + l15 * 4);
      float d0 = e.x - cv.x, d1 = e.y - cv.y, d2 = e.z - cv.z, d3 = e.w - cv.w;
      sse += d0 * d0 + d1 * d1 + d2 * d2 + d3 * d3;
      bf16x4 q;
      q[0] = (bf16)e.x; q[1] = (bf16)e.y; q[2] = (bf16)e.z; q[3] = (bf16)e.w;
      *(bf16x4*)(qbf + (size_t)rowg * EDIM + l15 * 4) = q;
      if (l15 == 0) atomicAdd(&lhist[idx], 1u);
    }
  }

  // wave-reduce SSE -> per-wave partial -> block reduce -> one global atomic
#pragma unroll
  for (int m = 1; m < 64; m <<= 1) sse += __shfl_xor(sse, m);
  if (lane == 0) swse[wave] = sse;
  __syncthreads();

  unsigned v = lhist[tid];
  if (v) atomicAdd(hist + tid, v);
  if (tid == 0) {
    float s = 0.f;
#pragma unroll
    for (int w = 0; w < 8; ++w) s += swse[w];
    atomicAdd(sse_out, s);
  }
}

// ---------------------------------------------------------------- finalize: vq_loss + perplexity
__global__ void finalize_k(const unsigned* __restrict__ hist, const float* __restrict__ sse,
                           float* __restrict__ out_tail) {
  __shared__ float red[512];
  int t = threadIdx.x;
  float p = (float)hist[t] * (1.0f / (float)NCODES);
  red[t] = p * logf(p + 1e-10f);
  __syncthreads();
  for (int s = 256; s > 0; s >>= 1) {
    if (t < s) red[t] += red[t + s];
    __syncthreads();
  }
  if (t == 0) {
    out_tail[0] = 1.25f * sse[0] * (1.0f / ((float)NCODES * (float)EDIM));  // q + 0.25*e latent loss
    out_tail[1] = expf(-red[0]);                                            // perplexity
  }
}

// ---------------------------------------------------------------- launch
extern "C" void kernel_launch(void* const* d_in, const int* in_sizes, int n_in,
                              void* d_out, int out_size, void* d_ws, size_t ws_size,
                              hipStream_t stream) {
  const float* x  = (const float*)d_in[0];
  const float* W1 = (const float*)d_in[1];
  const float* b1 = (const float*)d_in[2];
  const float* W2 = (const float*)d_in[3];
  const float* b2 = (const float*)d_in[4];
  const float* W3 = (const float*)d_in[5];
  const float* b3 = (const float*)d_in[6];
  const float* W4 = (const float*)d_in[7];
  const float* b4 = (const float*)d_in[8];
  const float* cb = (const float*)d_in[9];
  float* out = (float*)d_out;

  char* ws = (char*)d_ws;
  float*    sse    = (float*)(ws + 0);        // 4 B
  unsigned* hist   = (unsigned*)(ws + 1024);  // 2 KB
  float*    cbnorm = (float*)(ws + 4096);     // 2 KB
  bf16*     cbbf   = (bf16*)(ws + 8192);      // 64 KB
  size_t off = 131072;
  bf16* xbf  = (bf16*)(ws + off);  off += (size_t)NB * NF * 2;   // 33.5 MB
  bf16* wbuf = (bf16*)(ws + off);  off += (size_t)NB * NF * 2;   // 33.5 MB (reused for W1..W4)
  bf16* hbf  = (bf16*)(ws + off);  off += (size_t)NB * NF * 2;   // 33.5 MB
  float* latent = (float*)(ws + off); off += (size_t)NB * NF * 4; // 67 MB
  bf16* qbf  = xbf;   // alias: x dead after GEMM1
  bf16* h2bf = hbf;   // alias: h dead after GEMM2

  hipMemsetAsync(ws, 0, 3072, stream);  // sse + hist

  const int n8 = NB * NF / 8;
  cvt_f32_bf16<<<dim3(2048), dim3(256), 0, stream>>>(x,  xbf,  n8);
  cvt_f32_bf16<<<dim3(2048), dim3(256), 0, stream>>>(W1, wbuf, n8);
  cbprep<<<dim3(2), dim3(256), 0, stream>>>(cb, cbbf, cbnorm);

  dim3 ggrid(32, 32), gblock(256);
  // h = relu(x @ W1^T + b1) -> bf16
  gemm_bt<1, 1><<<ggrid, gblock, 0, stream>>>(xbf, wbuf, b1, (float*)nullptr, hbf);
  cvt_f32_bf16<<<dim3(2048), dim3(256), 0, stream>>>(W2, wbuf, n8);
  // latent = h @ W2^T + b2 -> f32
  gemm_bt<0, 0><<<ggrid, gblock, 0, stream>>>(hbf, wbuf, b2, latent, (bf16*)nullptr);
  // VQ: argmin, quantized (bf16), histogram, SSE
  vq_kernel<<<dim3(512), dim3(512), 0, stream>>>(latent, cb, cbbf, cbnorm, qbf, hist, sse);
  cvt_f32_bf16<<<dim3(2048), dim3(256), 0, stream>>>(W3, wbuf, n8);
  // h2 = relu(q @ W3^T + b3) -> bf16
  gemm_bt<1, 1><<<ggrid, gblock, 0, stream>>>(qbf, wbuf, b3, (float*)nullptr, h2bf);
  cvt_f32_bf16<<<dim3(2048), dim3(256), 0, stream>>>(W4, wbuf, n8);
  // recons = h2 @ W4^T + b4 -> f32 (d_out)
  gemm_bt<0, 0><<<ggrid, gblock, 0, stream>>>(h2bf, wbuf, b4, out, (bf16*)nullptr);

  finalize_k<<<dim3(1), dim3(512), 0, stream>>>(hist, sse, out + (size_t)NB * NF);
}

// Round 3
// 747.665 us; speedup vs baseline: 1.4051x; 1.1324x over previous
//
#include <hip/hip_runtime.h>
#include <stdint.h>
#include <stddef.h>

typedef __bf16 bf16;
typedef __bf16 bf16x8 __attribute__((ext_vector_type(8)));
typedef __bf16 bf16x4 __attribute__((ext_vector_type(4)));
typedef float  f32x4  __attribute__((ext_vector_type(4)));

#define NB      4096        // batch
#define NF      4096        // features (= K = N for all GEMMs)
#define NCODES  (NB * NF / 64)   // 262144
#define NEMB    512
#define EDIM    64

// ---------------------------------------------------------------- helpers
__device__ __forceinline__ void gld_lds16(const void* g, void* l) {
  __builtin_amdgcn_global_load_lds(
      (const __attribute__((address_space(1))) void*)g,
      (__attribute__((address_space(3))) void*)l, 16, 0, 0);
}

// ---------------------------------------------------------------- f32 -> bf16 convert
__global__ void cvt_f32_bf16(const float* __restrict__ in, bf16* __restrict__ out, int n8) {
  int idx = blockIdx.x * blockDim.x + threadIdx.x;
  int stride = gridDim.x * blockDim.x;
  for (int i = idx; i < n8; i += stride) {
    const float4* p = (const float4*)(in + (size_t)i * 8);
    float4 a = p[0], b = p[1];
    bf16x8 o;
    o[0] = (bf16)a.x; o[1] = (bf16)a.y; o[2] = (bf16)a.z; o[3] = (bf16)a.w;
    o[4] = (bf16)b.x; o[5] = (bf16)b.y; o[6] = (bf16)b.z; o[7] = (bf16)b.w;
    *(bf16x8*)(out + (size_t)i * 8) = o;
  }
}

// ---------------------------------------------------------------- codebook prep: bf16 copy + row norms
__global__ void cbprep(const float* __restrict__ cb, bf16* __restrict__ cbbf,
                       float* __restrict__ cbnorm) {
  int r = blockIdx.x * blockDim.x + threadIdx.x;
  if (r < NEMB) {
    float s = 0.f;
    for (int d = 0; d < EDIM; ++d) {
      float v = cb[r * EDIM + d];
      s += v * v;
      cbbf[r * EDIM + d] = (bf16)v;
    }
    cbnorm[r] = s;
  }
}

// ---------------------------------------------------------------- GEMM 256x256 8-phase (T2+T3+T4+T5)
// C = act(A @ W^T + bias). A:[4096,4096] bf16 rm, W:[4096,4096] bf16 rm.
// 8 waves (2M x 4N), per-wave 128x64 out = 8x4 frags of 16x16, BK=64.
// LDS 128 KiB: AS/BS [2 dbuf][2 half][128*64], 16B-slot swizzle s^=(r&7)
// (applied inverse on global src for the linear global_load_lds dest).
// Phase q of tile t: {ds_read subtile; stage 1 half; bar; lgkm0; prio1;
// 16 MFMA (quadrant q); prio0; [q3: vmcnt(6)]; bar}.
// Stage slots: q0->A1(t+1), q1->B0(t+2), q2->B1(t+2), q3->A0(t+2) — each
// region's reads drained a barrier before its overwrite is issued.
__device__ __forceinline__ void rdfrag(const bf16* base, int r, int lg,
                                       bf16x8& v0, bf16x8& v1) {
  int s0 = lg ^ (r & 7);
  int s1 = (lg + 4) ^ (r & 7);
  v0 = *(const bf16x8*)(base + r * 64 + s0 * 8);
  v1 = *(const bf16x8*)(base + r * 64 + s1 * 8);
}

template<int OUTMODE, int RELU>   // OUTMODE: 0 f32, 1 bf16
__global__ __launch_bounds__(512, 2)
void gemm256(const bf16* __restrict__ A, const bf16* __restrict__ W,
             const float* __restrict__ bias,
             float* __restrict__ outF, bf16* __restrict__ outB) {
  constexpr int K = 4096, N = 4096, NT = 64;
  __shared__ bf16 AS[2][2][128 * 64];
  __shared__ bf16 BS[2][2][128 * 64];

  const int tid = threadIdx.x;
  const int wave = tid >> 6, lane = tid & 63;
  const int l15 = lane & 15, lg = lane >> 4;
  const int wm = wave >> 2, wn = wave & 3;

  // XCD-bijective swizzle (256 blocks, 256 % 8 == 0)
  const int bid = blockIdx.x;
  const int lb  = (bid & 7) * 32 + (bid >> 3);
  const int bx = lb & 15, by = lb >> 4;
  const int brow = by * 256, bcol = bx * 256;

  // staging decomposition: thread handles units u1,u2 of each 1024-unit half
  const int u1 = tid,       r1 = u1 >> 3, ss1 = (u1 & 7) ^ (r1 & 7);
  const int u2 = tid + 512, r2 = u2 >> 3, ss2 = (u2 & 7) ^ (r2 & 7);

#define STAGE(gbase, row0, kt_, ldsh) do {                                        \
    gld_lds16((gbase) + (size_t)((row0) + r1) * K + (kt_) * 64 + ss1 * 8, (ldsh) + u1 * 8); \
    gld_lds16((gbase) + (size_t)((row0) + r2) * K + (kt_) * 64 + ss2 * 8, (ldsh) + u2 * 8); \
  } while (0)

  f32x4 acc[8][4];
#pragma unroll
  for (int i = 0; i < 8; ++i)
#pragma unroll
    for (int j = 0; j < 4; ++j)
      acc[i][j] = f32x4{0.f, 0.f, 0.f, 0.f};

  // prologue: 7 halves (tile0 complete + tile1 B0,B1,A0); vmcnt(6) -> tile0 landed
  STAGE(W, bcol,       0, &BS[0][0][0]);
  STAGE(W, bcol + 128, 0, &BS[0][1][0]);
  STAGE(A, brow,       0, &AS[0][0][0]);
  STAGE(A, brow + 128, 0, &AS[0][1][0]);
  STAGE(W, bcol,       1, &BS[1][0][0]);
  STAGE(W, bcol + 128, 1, &BS[1][1][0]);
  STAGE(A, brow,       1, &AS[1][0][0]);
  asm volatile("s_waitcnt vmcnt(6)" ::: "memory");
  __builtin_amdgcn_s_barrier();

  const int rb0 = (wn & 1) * 64;
  for (int kt = 0; kt < NT; ++kt) {
    const int par = kt & 1;
    const bf16* Ab = &AS[par][wm][0];
    const bf16* Bb = &BS[par][wn >> 1][0];

    bf16x8 b0[4], b1[4], a0[2], a1[2], c0[2], c1[2];

    // ---- phase 0: read B (8) + A i=0,1 (4); stage A1(t+1); MFMA quad 0
#pragma unroll
    for (int j = 0; j < 4; ++j) rdfrag(Bb, rb0 + j * 16 + l15, lg, b0[j], b1[j]);
    rdfrag(Ab, 0 * 16 + l15, lg, a0[0], a1[0]);
    rdfrag(Ab, 1 * 16 + l15, lg, a0[1], a1[1]);
    STAGE(A, brow + 128, (kt + 1) & (NT - 1), &AS[(kt + 1) & 1][1][0]);
    __builtin_amdgcn_s_barrier();
    asm volatile("s_waitcnt lgkmcnt(0)" ::: "memory");
    __builtin_amdgcn_s_setprio(1);
#pragma unroll
    for (int i2 = 0; i2 < 2; ++i2)
#pragma unroll
      for (int j = 0; j < 4; ++j) {
        acc[i2][j] = __builtin_amdgcn_mfma_f32_16x16x32_bf16(a0[i2], b0[j], acc[i2][j], 0, 0, 0);
        acc[i2][j] = __builtin_amdgcn_mfma_f32_16x16x32_bf16(a1[i2], b1[j], acc[i2][j], 0, 0, 0);
      }
    __builtin_amdgcn_s_setprio(0);
    __builtin_amdgcn_s_barrier();

    // ---- phase 1: read A i=2,3 (4); stage B0(t+2); MFMA quad 1
    rdfrag(Ab, 2 * 16 + l15, lg, a0[0], a1[0]);
    rdfrag(Ab, 3 * 16 + l15, lg, a0[1], a1[1]);
    STAGE(W, bcol, (kt + 2) & (NT - 1), &BS[par][0][0]);
    __builtin_amdgcn_s_barrier();
    asm volatile("s_waitcnt lgkmcnt(0)" ::: "memory");
    __builtin_amdgcn_s_setprio(1);
#pragma unroll
    for (int i2 = 0; i2 < 2; ++i2)
#pragma unroll
      for (int j = 0; j < 4; ++j) {
        acc[2 + i2][j] = __builtin_amdgcn_mfma_f32_16x16x32_bf16(a0[i2], b0[j], acc[2 + i2][j], 0, 0, 0);
        acc[2 + i2][j] = __builtin_amdgcn_mfma_f32_16x16x32_bf16(a1[i2], b1[j], acc[2 + i2][j], 0, 0, 0);
      }
    __builtin_amdgcn_s_setprio(0);
    __builtin_amdgcn_s_barrier();

    // ---- phase 2: read A i=4..7 (8); stage B1(t+2); MFMA quad 2
    rdfrag(Ab, 4 * 16 + l15, lg, a0[0], a1[0]);
    rdfrag(Ab, 5 * 16 + l15, lg, a0[1], a1[1]);
    rdfrag(Ab, 6 * 16 + l15, lg, c0[0], c1[0]);
    rdfrag(Ab, 7 * 16 + l15, lg, c0[1], c1[1]);
    STAGE(W, bcol + 128, (kt + 2) & (NT - 1), &BS[par][1][0]);
    __builtin_amdgcn_s_barrier();
    asm volatile("s_waitcnt lgkmcnt(0)" ::: "memory");
    __builtin_amdgcn_s_setprio(1);
#pragma unroll
    for (int i2 = 0; i2 < 2; ++i2)
#pragma unroll
      for (int j = 0; j < 4; ++j) {
        acc[4 + i2][j] = __builtin_amdgcn_mfma_f32_16x16x32_bf16(a0[i2], b0[j], acc[4 + i2][j], 0, 0, 0);
        acc[4 + i2][j] = __builtin_amdgcn_mfma_f32_16x16x32_bf16(a1[i2], b1[j], acc[4 + i2][j], 0, 0, 0);
      }
    __builtin_amdgcn_s_setprio(0);
    __builtin_amdgcn_s_barrier();

    // ---- phase 3: no reads; stage A0(t+2); MFMA quad 3; vmcnt(6) -> tile t+1 landed
    STAGE(A, brow, (kt + 2) & (NT - 1), &AS[par][0][0]);
    __builtin_amdgcn_s_barrier();
    __builtin_amdgcn_s_setprio(1);
#pragma unroll
    for (int i2 = 0; i2 < 2; ++i2)
#pragma unroll
      for (int j = 0; j < 4; ++j) {
        acc[6 + i2][j] = __builtin_amdgcn_mfma_f32_16x16x32_bf16(c0[i2], b0[j], acc[6 + i2][j], 0, 0, 0);
        acc[6 + i2][j] = __builtin_amdgcn_mfma_f32_16x16x32_bf16(c1[i2], b1[j], acc[6 + i2][j], 0, 0, 0);
      }
    __builtin_amdgcn_s_setprio(0);
    asm volatile("s_waitcnt vmcnt(6)" ::: "memory");
    __builtin_amdgcn_s_barrier();
  }
#undef STAGE

  // epilogue: C/D layout col = lane&15, row = (lane>>4)*4 + reg
#pragma unroll
  for (int j = 0; j < 4; ++j) {
    int col = bcol + wn * 64 + j * 16 + l15;
    float bv = bias[col];
#pragma unroll
    for (int i = 0; i < 8; ++i) {
#pragma unroll
      for (int rr = 0; rr < 4; ++rr) {
        int row = brow + wm * 128 + i * 16 + lg * 4 + rr;
        float v = acc[i][j][rr] + bv;
        if (RELU) v = fmaxf(v, 0.f);
        size_t o = (size_t)row * N + col;
        if (OUTMODE == 0) outF[o] = v;
        else              outB[o] = (bf16)v;
      }
    }
  }
}

// ---------------------------------------------------------------- VQ: LDS codebook, 4-group ILP,
// packed-key argmin reduce, 1 SSE atomic/block, per-block hist flush.
__global__ __launch_bounds__(512, 2)
void vq_kernel(const float* __restrict__ latent,
               const float* __restrict__ cb, const bf16* __restrict__ cbbf_g,
               const float* __restrict__ cbnorm_g,
               bf16* __restrict__ qbf, unsigned int* __restrict__ hist,
               float* __restrict__ sse_out) {
  __shared__ bf16     cbl[NEMB * EDIM];   // 64 KB, XOR-swizzled at 16B granularity
  __shared__ float    cnl[NEMB];
  __shared__ unsigned lhist[NEMB];
  __shared__ float    swse[8];

  const int tid = threadIdx.x;
  lhist[tid] = 0;
  cnl[tid] = cbnorm_g[tid];
  {
    const uint4* src = (const uint4*)cbbf_g;   // 4096 16B units
    uint4* dst = (uint4*)cbl;
#pragma unroll
    for (int i = 0; i < 8; ++i) {
      int u = tid + i * 512;
      dst[u ^ ((u >> 3) & 7)] = src[u];
    }
  }
  __syncthreads();

  const int wave = tid >> 6, lane = tid & 63;
  const int l15 = lane & 15, lg = lane >> 4;
  const int base = blockIdx.x * 512 + wave * 64;

  bf16x8 a0[4], a1[4];
#pragma unroll
  for (int g = 0; g < 4; ++g) {
    const float* ap = latent + (size_t)(base + g * 16 + l15) * EDIM + lg * 8;
    float4 f0 = *(const float4*)(ap);
    float4 f1 = *(const float4*)(ap + 4);
    float4 f2 = *(const float4*)(ap + 32);
    float4 f3 = *(const float4*)(ap + 36);
    bf16x8 t0, t1;
    t0[0]=(bf16)f0.x; t0[1]=(bf16)f0.y; t0[2]=(bf16)f0.z; t0[3]=(bf16)f0.w;
    t0[4]=(bf16)f1.x; t0[5]=(bf16)f1.y; t0[6]=(bf16)f1.z; t0[7]=(bf16)f1.w;
    t1[0]=(bf16)f2.x; t1[1]=(bf16)f2.y; t1[2]=(bf16)f2.z; t1[3]=(bf16)f2.w;
    t1[4]=(bf16)f3.x; t1[5]=(bf16)f3.y; t1[6]=(bf16)f3.z; t1[7]=(bf16)f3.w;
    a0[g] = t0; a1[g] = t1;
  }

  float best[4][4];
  int   bidx[4][4];
#pragma unroll
  for (int g = 0; g < 4; ++g)
#pragma unroll
    for (int r = 0; r < 4; ++r) { best[g][r] = 1e30f; bidx[g][r] = 0; }

  for (int ct = 0; ct < 32; ++ct) {
    const int row = ct * 16 + l15;
    const int u0 = ((row << 3) + lg) ^ (row & 7);
    bf16x8 b0 = *(const bf16x8*)(cbl + u0 * 8);
    bf16x8 b1 = *(const bf16x8*)(cbl + (u0 ^ 4) * 8);
    float cn = cnl[row];
    int   c  = row;
#pragma unroll
    for (int g = 0; g < 4; ++g) {
      f32x4 acc = f32x4{0.f, 0.f, 0.f, 0.f};
      acc = __builtin_amdgcn_mfma_f32_16x16x32_bf16(a0[g], b0, acc, 0, 0, 0);
      acc = __builtin_amdgcn_mfma_f32_16x16x32_bf16(a1[g], b1, acc, 0, 0, 0);
#pragma unroll
      for (int r = 0; r < 4; ++r) {
        float s = fmaf(-2.0f, acc[r], cn);
        if (s < best[g][r]) { best[g][r] = s; bidx[g][r] = c; }
      }
    }
  }

  float sse = 0.f;
#pragma unroll
  for (int g = 0; g < 4; ++g) {
#pragma unroll
    for (int r = 0; r < 4; ++r) {
      uint32_t bits = __float_as_uint(best[g][r]);
      uint32_t u = bits ^ ((uint32_t)((int32_t)bits >> 31) | 0x80000000u);
      uint32_t key = (u & 0xFFFFFE00u) | (uint32_t)bidx[g][r];
#pragma unroll
      for (int m = 1; m < 16; m <<= 1) {
        uint32_t o = __shfl_xor(key, m);
        key = (o < key) ? o : key;
      }
      int idx = (int)(key & 511u);
      int rowg = base + g * 16 + lg * 4 + r;
      float4 cv = *(const float4*)(latent + (size_t)rowg * EDIM + l15 * 4);
      float4 e  = *(const float4*)(cb + (size_t)idx * EDIM + l15 * 4);
      float d0 = e.x - cv.x, d1 = e.y - cv.y, d2 = e.z - cv.z, d3 = e.w - cv.w;
      sse += d0 * d0 + d1 * d1 + d2 * d2 + d3 * d3;
      bf16x4 q;
      q[0] = (bf16)e.x; q[1] = (bf16)e.y; q[2] = (bf16)e.z; q[3] = (bf16)e.w;
      *(bf16x4*)(qbf + (size_t)rowg * EDIM + l15 * 4) = q;
      if (l15 == 0) atomicAdd(&lhist[idx], 1u);
    }
  }

#pragma unroll
  for (int m = 1; m < 64; m <<= 1) sse += __shfl_xor(sse, m);
  if (lane == 0) swse[wave] = sse;
  __syncthreads();

  unsigned v = lhist[tid];
  if (v) atomicAdd(hist + tid, v);
  if (tid == 0) {
    float s = 0.f;
#pragma unroll
    for (int w = 0; w < 8; ++w) s += swse[w];
    atomicAdd(sse_out, s);
  }
}

// ---------------------------------------------------------------- finalize: vq_loss + perplexity
__global__ void finalize_k(const unsigned* __restrict__ hist, const float* __restrict__ sse,
                           float* __restrict__ out_tail) {
  __shared__ float red[512];
  int t = threadIdx.x;
  float p = (float)hist[t] * (1.0f / (float)NCODES);
  red[t] = p * logf(p + 1e-10f);
  __syncthreads();
  for (int s = 256; s > 0; s >>= 1) {
    if (t < s) red[t] += red[t + s];
    __syncthreads();
  }
  if (t == 0) {
    out_tail[0] = 1.25f * sse[0] * (1.0f / ((float)NCODES * (float)EDIM));
    out_tail[1] = expf(-red[0]);
  }
}

// ---------------------------------------------------------------- launch
extern "C" void kernel_launch(void* const* d_in, const int* in_sizes, int n_in,
                              void* d_out, int out_size, void* d_ws, size_t ws_size,
                              hipStream_t stream) {
  const float* x  = (const float*)d_in[0];
  const float* W1 = (const float*)d_in[1];
  const float* b1 = (const float*)d_in[2];
  const float* W2 = (const float*)d_in[3];
  const float* b2 = (const float*)d_in[4];
  const float* W3 = (const float*)d_in[5];
  const float* b3 = (const float*)d_in[6];
  const float* W4 = (const float*)d_in[7];
  const float* b4 = (const float*)d_in[8];
  const float* cb = (const float*)d_in[9];
  float* out = (float*)d_out;

  char* ws = (char*)d_ws;
  float*    sse    = (float*)(ws + 0);
  unsigned* hist   = (unsigned*)(ws + 1024);
  float*    cbnorm = (float*)(ws + 4096);
  bf16*     cbbf   = (bf16*)(ws + 8192);
  size_t off = 131072;
  bf16* xbf  = (bf16*)(ws + off);  off += (size_t)NB * NF * 2;
  bf16* wbuf = (bf16*)(ws + off);  off += (size_t)NB * NF * 2;
  bf16* hbf  = (bf16*)(ws + off);  off += (size_t)NB * NF * 2;
  float* latent = (float*)(ws + off); off += (size_t)NB * NF * 4;
  bf16* qbf  = xbf;   // alias: x dead after GEMM1
  bf16* h2bf = hbf;   // alias: h dead after GEMM2

  hipMemsetAsync(ws, 0, 3072, stream);  // sse + hist

  const int n8 = NB * NF / 8;
  cvt_f32_bf16<<<dim3(2048), dim3(256), 0, stream>>>(x,  xbf,  n8);
  cvt_f32_bf16<<<dim3(2048), dim3(256), 0, stream>>>(W1, wbuf, n8);
  cbprep<<<dim3(2), dim3(256), 0, stream>>>(cb, cbbf, cbnorm);

  dim3 ggrid(256), gblock(512);
  // h = relu(x @ W1^T + b1) -> bf16
  gemm256<1, 1><<<ggrid, gblock, 0, stream>>>(xbf, wbuf, b1, (float*)nullptr, hbf);
  cvt_f32_bf16<<<dim3(2048), dim3(256), 0, stream>>>(W2, wbuf, n8);
  // latent = h @ W2^T + b2 -> f32
  gemm256<0, 0><<<ggrid, gblock, 0, stream>>>(hbf, wbuf, b2, latent, (bf16*)nullptr);
  // VQ
  vq_kernel<<<dim3(512), dim3(512), 0, stream>>>(latent, cb, cbbf, cbnorm, qbf, hist, sse);
  cvt_f32_bf16<<<dim3(2048), dim3(256), 0, stream>>>(W3, wbuf, n8);
  // h2 = relu(q @ W3^T + b3) -> bf16
  gemm256<1, 1><<<ggrid, gblock, 0, stream>>>(qbf, wbuf, b3, (float*)nullptr, h2bf);
  cvt_f32_bf16<<<dim3(2048), dim3(256), 0, stream>>>(W4, wbuf, n8);
  // recons = h2 @ W4^T + b4 -> f32 (d_out)
  gemm256<0, 0><<<ggrid, gblock, 0, stream>>>(h2bf, wbuf, b4, out, (bf16*)nullptr);

  finalize_k<<<dim3(1), dim3(512), 0, stream>>>(hist, sse, out + (size_t)NB * NF);
}

// Round 4
// 602.528 us; speedup vs baseline: 1.7436x; 1.2409x over previous
//
#include <hip/hip_runtime.h>
#include <stdint.h>
#include <stddef.h>

typedef __bf16 bf16;
typedef __bf16 bf16x8 __attribute__((ext_vector_type(8)));
typedef __bf16 bf16x4 __attribute__((ext_vector_type(4)));
typedef float  f32x4  __attribute__((ext_vector_type(4)));

#define NB      4096        // batch
#define NF      4096        // features (= K = N for all GEMMs)
#define NCODES  (NB * NF / 64)   // 262144
#define NEMB    512
#define EDIM    64

// ---------------------------------------------------------------- helpers
__device__ __forceinline__ void gld_lds16(const void* g, void* l) {
  __builtin_amdgcn_global_load_lds(
      (const __attribute__((address_space(1))) void*)g,
      (__attribute__((address_space(3))) void*)l, 16, 0, 0);
}

// ---------------------------------------------------------------- f32 -> bf16 convert
__global__ void cvt_f32_bf16(const float* __restrict__ in, bf16* __restrict__ out, int n8) {
  int idx = blockIdx.x * blockDim.x + threadIdx.x;
  int stride = gridDim.x * blockDim.x;
  for (int i = idx; i < n8; i += stride) {
    const float4* p = (const float4*)(in + (size_t)i * 8);
    float4 a = p[0], b = p[1];
    bf16x8 o;
    o[0] = (bf16)a.x; o[1] = (bf16)a.y; o[2] = (bf16)a.z; o[3] = (bf16)a.w;
    o[4] = (bf16)b.x; o[5] = (bf16)b.y; o[6] = (bf16)b.z; o[7] = (bf16)b.w;
    *(bf16x8*)(out + (size_t)i * 8) = o;
  }
}

// ---------------------------------------------------------------- codebook prep: bf16 copy + row norms
__global__ void cbprep(const float* __restrict__ cb, bf16* __restrict__ cbbf,
                       float* __restrict__ cbnorm) {
  int r = blockIdx.x * blockDim.x + threadIdx.x;
  if (r < NEMB) {
    float s = 0.f;
    for (int d = 0; d < EDIM; ++d) {
      float v = cb[r * EDIM + d];
      s += v * v;
      cbbf[r * EDIM + d] = (bf16)v;
    }
    cbnorm[r] = s;
  }
}

// ---------------------------------------------------------------- GEMM 256x256, true 8-phase/2-tile
// pipeline (T2+T3+T4+T5): ds_reads issued one phase AHEAD of their MFMA, counted
// lgkmcnt waits only for the previous phase's reads -> LDS drain hides under MFMA.
// 8 waves (2M x 4N), per-wave 128x64 out, BK=64, LDS 128 KiB, 16B-slot XOR swizzle.
__device__ __forceinline__ void rdfrag(const bf16* base, int r, int lg,
                                       bf16x8& v0, bf16x8& v1) {
  int s0 = lg ^ (r & 7);
  int s1 = (lg + 4) ^ (r & 7);
  v0 = *(const bf16x8*)(base + r * 64 + s0 * 8);
  v1 = *(const bf16x8*)(base + r * 64 + s1 * 8);
}

#define BAR()   __builtin_amdgcn_s_barrier()
#define LGKM(n) asm volatile("s_waitcnt lgkmcnt(" #n ")" ::: "memory")
#define VMC(n)  asm volatile("s_waitcnt vmcnt(" #n ")" ::: "memory")
#define PRIO(n) __builtin_amdgcn_s_setprio(n)

#define RD_A(s0, s1, base, q) do {                                   \
    rdfrag(base, (2*(q))*16   + l15, lg, s0[0], s1[0]);              \
    rdfrag(base, (2*(q)+1)*16 + l15, lg, s0[1], s1[1]); } while (0)

#define RD_B(s0, s1, base) do {                                      \
    rdfrag(base, rb0 + 0*16 + l15, lg, s0[0], s1[0]);                \
    rdfrag(base, rb0 + 1*16 + l15, lg, s0[1], s1[1]);                \
    rdfrag(base, rb0 + 2*16 + l15, lg, s0[2], s1[2]);                \
    rdfrag(base, rb0 + 3*16 + l15, lg, s0[3], s1[3]); } while (0)

#define MFMA_Q(q, x0, x1, y0, y1) do {                               \
    _Pragma("unroll")                                                \
    for (int i2 = 0; i2 < 2; ++i2) {                                 \
      _Pragma("unroll")                                              \
      for (int j = 0; j < 4; ++j) {                                  \
        acc[2*(q)+i2][j] = __builtin_amdgcn_mfma_f32_16x16x32_bf16(  \
            x0[i2], y0[j], acc[2*(q)+i2][j], 0, 0, 0);               \
        acc[2*(q)+i2][j] = __builtin_amdgcn_mfma_f32_16x16x32_bf16(  \
            x1[i2], y1[j], acc[2*(q)+i2][j], 0, 0, 0);               \
      } } } while (0)

template<int OUTMODE, int RELU>   // OUTMODE: 0 f32, 1 bf16
__global__ __launch_bounds__(512, 2)
void gemm256(const bf16* __restrict__ A, const bf16* __restrict__ W,
             const float* __restrict__ bias,
             float* __restrict__ outF, bf16* __restrict__ outB) {
  constexpr int K = 4096, N = 4096, NT = 64;
  __shared__ bf16 AS[2][2][128 * 64];
  __shared__ bf16 BS[2][2][128 * 64];

  const int tid = threadIdx.x;
  const int wave = tid >> 6, lane = tid & 63;
  const int l15 = lane & 15, lg = lane >> 4;
  const int wm = wave >> 2, wn = wave & 3;
  const int rb0 = (wn & 1) * 64;

  // XCD-bijective swizzle (256 blocks, 256 % 8 == 0)
  const int bid = blockIdx.x;
  const int lb  = (bid & 7) * 32 + (bid >> 3);
  const int bx = lb & 15, by = lb >> 4;
  const int brow = by * 256, bcol = bx * 256;

  // staging decomposition: thread handles units u1,u2 of each 1024-unit half
  const int u1 = tid,       r1 = u1 >> 3, ss1 = (u1 & 7) ^ (r1 & 7);
  const int u2 = tid + 512, r2 = u2 >> 3, ss2 = (u2 & 7) ^ (r2 & 7);

#define STAGE(gbase, row0, kt_, ldsh) do {                                                  \
    gld_lds16((gbase) + (size_t)((row0) + r1) * K + (kt_) * 64 + ss1 * 8, (ldsh) + u1 * 8); \
    gld_lds16((gbase) + (size_t)((row0) + r2) * K + (kt_) * 64 + ss2 * 8, (ldsh) + u2 * 8); \
  } while (0)

  // wave-local LDS base pointers (loop-invariant; parity explicit)
  const bf16* A0b = &AS[0][wm][0];
  const bf16* A1b = &AS[1][wm][0];
  const bf16* B0b = &BS[0][wn >> 1][0];
  const bf16* B1b = &BS[1][wn >> 1][0];

  f32x4 acc[8][4];
#pragma unroll
  for (int i = 0; i < 8; ++i)
#pragma unroll
    for (int j = 0; j < 4; ++j)
      acc[i][j] = f32x4{0.f, 0.f, 0.f, 0.f};

  bf16x8 bE0[4], bE1[4], bO0[4], bO1[4];   // B frag sets (even / odd tile)
  bf16x8 aP0[2], aP1[2], aQ0[2], aQ1[2];   // A frag ping-pong sets

  // prologue: 7 halves (tile0 complete + tile1 B0,B1,A0); vmcnt(6) -> tile0 landed
  STAGE(W, bcol,       0, &BS[0][0][0]);
  STAGE(W, bcol + 128, 0, &BS[0][1][0]);
  STAGE(A, brow,       0, &AS[0][0][0]);
  STAGE(A, brow + 128, 0, &AS[0][1][0]);
  STAGE(W, bcol,       1, &BS[1][0][0]);
  STAGE(W, bcol + 128, 1, &BS[1][1][0]);
  STAGE(A, brow,       1, &AS[1][0][0]);
  VMC(6);
  BAR();
  RD_B(bE0, bE1, B0b);          // B(T0)
  RD_A(aP0, aP1, A0b, 0);       // A(T0,q0)   (drained by P0's lgkm(4))

  for (int kt = 0; kt < NT; kt += 2) {
    // ---- P0: read A(T0,q1); stage A1(T1); MFMA T0q0
    RD_A(aQ0, aQ1, A0b, 1);
    STAGE(A, brow + 128, kt + 1, &AS[1][1][0]);
    BAR(); LGKM(4); PRIO(1);
    MFMA_Q(0, aP0, aP1, bE0, bE1);
    PRIO(0); BAR();

    // ---- P1: read A(T0,q2); stage B0(T2); MFMA T0q1
    RD_A(aP0, aP1, A0b, 2);
    STAGE(W, bcol, (kt + 2) & (NT - 1), &BS[0][0][0]);
    BAR(); LGKM(4); PRIO(1);
    MFMA_Q(1, aQ0, aQ1, bE0, bE1);
    PRIO(0); BAR();

    // ---- P2: read A(T0,q3); stage B1(T2); MFMA T0q2
    RD_A(aQ0, aQ1, A0b, 3);
    STAGE(W, bcol + 128, (kt + 2) & (NT - 1), &BS[0][1][0]);
    BAR(); LGKM(4); PRIO(1);
    MFMA_Q(2, aP0, aP1, bE0, bE1);
    PRIO(0); BAR();

    // ---- P3: vmcnt(4) certifies T1 landed; read B(T1)+A(T1,q0); stage A0(T2); MFMA T0q3
    VMC(4);
    RD_B(bO0, bO1, B1b);
    RD_A(aP0, aP1, A1b, 0);
    STAGE(A, brow, (kt + 2) & (NT - 1), &AS[0][0][0]);
    BAR(); LGKM(12); PRIO(1);
    MFMA_Q(3, aQ0, aQ1, bE0, bE1);
    PRIO(0); BAR();

    // ---- P4: read A(T1,q1); stage A1(T2); MFMA T1q0
    RD_A(aQ0, aQ1, A1b, 1);
    STAGE(A, brow + 128, (kt + 2) & (NT - 1), &AS[0][1][0]);
    BAR(); LGKM(4); PRIO(1);
    MFMA_Q(0, aP0, aP1, bO0, bO1);
    PRIO(0); BAR();

    // ---- P5: read A(T1,q2); stage B0(T3); MFMA T1q1
    RD_A(aP0, aP1, A1b, 2);
    STAGE(W, bcol, (kt + 3) & (NT - 1), &BS[1][0][0]);
    BAR(); LGKM(4); PRIO(1);
    MFMA_Q(1, aQ0, aQ1, bO0, bO1);
    PRIO(0); BAR();

    // ---- P6: read A(T1,q3); stage B1(T3); MFMA T1q2
    RD_A(aQ0, aQ1, A1b, 3);
    STAGE(W, bcol + 128, (kt + 3) & (NT - 1), &BS[1][1][0]);
    BAR(); LGKM(4); PRIO(1);
    MFMA_Q(2, aP0, aP1, bO0, bO1);
    PRIO(0); BAR();

    // ---- P7: vmcnt(4) certifies T2 landed; read B(T2)+A(T2,q0); stage A0(T3); MFMA T1q3
    VMC(4);
    RD_B(bE0, bE1, B0b);
    RD_A(aP0, aP1, A0b, 0);
    STAGE(A, brow, (kt + 3) & (NT - 1), &AS[1][0][0]);
    BAR(); LGKM(12); PRIO(1);
    MFMA_Q(3, aQ0, aQ1, bO0, bO1);
    PRIO(0); BAR();
  }
#undef STAGE

  // epilogue: C/D layout col = lane&15, row = (lane>>4)*4 + reg
#pragma unroll
  for (int j = 0; j < 4; ++j) {
    int col = bcol + wn * 64 + j * 16 + l15;
    float bv = bias[col];
#pragma unroll
    for (int i = 0; i < 8; ++i) {
#pragma unroll
      for (int rr = 0; rr < 4; ++rr) {
        int row = brow + wm * 128 + i * 16 + lg * 4 + rr;
        float v = acc[i][j][rr] + bv;
        if (RELU) v = fmaxf(v, 0.f);
        size_t o = (size_t)row * N + col;
        if (OUTMODE == 0) outF[o] = v;
        else              outB[o] = (bf16)v;
      }
    }
  }
}

// ---------------------------------------------------------------- VQ: LDS codebook, 4-group ILP,
// packed-key argmin reduce, 1 SSE atomic/block, per-block hist flush.
__global__ __launch_bounds__(512, 2)
void vq_kernel(const float* __restrict__ latent,
               const float* __restrict__ cb, const bf16* __restrict__ cbbf_g,
               const float* __restrict__ cbnorm_g,
               bf16* __restrict__ qbf, unsigned int* __restrict__ hist,
               float* __restrict__ sse_out) {
  __shared__ bf16     cbl[NEMB * EDIM];   // 64 KB, XOR-swizzled at 16B granularity
  __shared__ float    cnl[NEMB];
  __shared__ unsigned lhist[NEMB];
  __shared__ float    swse[8];

  const int tid = threadIdx.x;
  lhist[tid] = 0;
  cnl[tid] = cbnorm_g[tid];
  {
    const uint4* src = (const uint4*)cbbf_g;   // 4096 16B units
    uint4* dst = (uint4*)cbl;
#pragma unroll
    for (int i = 0; i < 8; ++i) {
      int u = tid + i * 512;
      dst[u ^ ((u >> 3) & 7)] = src[u];
    }
  }
  __syncthreads();

  const int wave = tid >> 6, lane = tid & 63;
  const int l15 = lane & 15, lg = lane >> 4;
  const int base = blockIdx.x * 512 + wave * 64;

  bf16x8 a0[4], a1[4];
#pragma unroll
  for (int g = 0; g < 4; ++g) {
    const float* ap = latent + (size_t)(base + g * 16 + l15) * EDIM + lg * 8;
    float4 f0 = *(const float4*)(ap);
    float4 f1 = *(const float4*)(ap + 4);
    float4 f2 = *(const float4*)(ap + 32);
    float4 f3 = *(const float4*)(ap + 36);
    bf16x8 t0, t1;
    t0[0]=(bf16)f0.x; t0[1]=(bf16)f0.y; t0[2]=(bf16)f0.z; t0[3]=(bf16)f0.w;
    t0[4]=(bf16)f1.x; t0[5]=(bf16)f1.y; t0[6]=(bf16)f1.z; t0[7]=(bf16)f1.w;
    t1[0]=(bf16)f2.x; t1[1]=(bf16)f2.y; t1[2]=(bf16)f2.z; t1[3]=(bf16)f2.w;
    t1[4]=(bf16)f3.x; t1[5]=(bf16)f3.y; t1[6]=(bf16)f3.z; t1[7]=(bf16)f3.w;
    a0[g] = t0; a1[g] = t1;
  }

  float best[4][4];
  int   bidx[4][4];
#pragma unroll
  for (int g = 0; g < 4; ++g)
#pragma unroll
    for (int r = 0; r < 4; ++r) { best[g][r] = 1e30f; bidx[g][r] = 0; }

  for (int ct = 0; ct < 32; ++ct) {
    const int row = ct * 16 + l15;
    const int u0 = ((row << 3) + lg) ^ (row & 7);
    bf16x8 b0 = *(const bf16x8*)(cbl + u0 * 8);
    bf16x8 b1 = *(const bf16x8*)(cbl + (u0 ^ 4) * 8);
    float cn = cnl[row];
    int   c  = row;
#pragma unroll
    for (int g = 0; g < 4; ++g) {
      f32x4 acc = f32x4{0.f, 0.f, 0.f, 0.f};
      acc = __builtin_amdgcn_mfma_f32_16x16x32_bf16(a0[g], b0, acc, 0, 0, 0);
      acc = __builtin_amdgcn_mfma_f32_16x16x32_bf16(a1[g], b1, acc, 0, 0, 0);
#pragma unroll
      for (int r = 0; r < 4; ++r) {
        float s = fmaf(-2.0f, acc[r], cn);
        if (s < best[g][r]) { best[g][r] = s; bidx[g][r] = c; }
      }
    }
  }

  float sse = 0.f;
#pragma unroll
  for (int g = 0; g < 4; ++g) {
#pragma unroll
    for (int r = 0; r < 4; ++r) {
      uint32_t bits = __float_as_uint(best[g][r]);
      uint32_t u = bits ^ ((uint32_t)((int32_t)bits >> 31) | 0x80000000u);
      uint32_t key = (u & 0xFFFFFE00u) | (uint32_t)bidx[g][r];
#pragma unroll
      for (int m = 1; m < 16; m <<= 1) {
        uint32_t o = __shfl_xor(key, m);
        key = (o < key) ? o : key;
      }
      int idx = (int)(key & 511u);
      int rowg = base + g * 16 + lg * 4 + r;
      float4 cv = *(const float4*)(latent + (size_t)rowg * EDIM + l15 * 4);
      float4 e  = *(const float4*)(cb + (size_t)idx * EDIM + l15 * 4);
      float d0 = e.x - cv.x, d1 = e.y - cv.y, d2 = e.z - cv.z, d3 = e.w - cv.w;
      sse += d0 * d0 + d1 * d1 + d2 * d2 + d3 * d3;
      bf16x4 q;
      q[0] = (bf16)e.x; q[1] = (bf16)e.y; q[2] = (bf16)e.z; q[3] = (bf16)e.w;
      *(bf16x4*)(qbf + (size_t)rowg * EDIM + l15 * 4) = q;
      if (l15 == 0) atomicAdd(&lhist[idx], 1u);
    }
  }

#pragma unroll
  for (int m = 1; m < 64; m <<= 1) sse += __shfl_xor(sse, m);
  if (lane == 0) swse[wave] = sse;
  __syncthreads();

  unsigned v = lhist[tid];
  if (v) atomicAdd(hist + tid, v);
  if (tid == 0) {
    float s = 0.f;
#pragma unroll
    for (int w = 0; w < 8; ++w) s += swse[w];
    atomicAdd(sse_out, s);
  }
}

// ---------------------------------------------------------------- finalize: vq_loss + perplexity
__global__ void finalize_k(const unsigned* __restrict__ hist, const float* __restrict__ sse,
                           float* __restrict__ out_tail) {
  __shared__ float red[512];
  int t = threadIdx.x;
  float p = (float)hist[t] * (1.0f / (float)NCODES);
  red[t] = p * logf(p + 1e-10f);
  __syncthreads();
  for (int s = 256; s > 0; s >>= 1) {
    if (t < s) red[t] += red[t + s];
    __syncthreads();
  }
  if (t == 0) {
    out_tail[0] = 1.25f * sse[0] * (1.0f / ((float)NCODES * (float)EDIM));
    out_tail[1] = expf(-red[0]);
  }
}

// ---------------------------------------------------------------- launch
extern "C" void kernel_launch(void* const* d_in, const int* in_sizes, int n_in,
                              void* d_out, int out_size, void* d_ws, size_t ws_size,
                              hipStream_t stream) {
  const float* x  = (const float*)d_in[0];
  const float* W1 = (const float*)d_in[1];
  const float* b1 = (const float*)d_in[2];
  const float* W2 = (const float*)d_in[3];
  const float* b2 = (const float*)d_in[4];
  const float* W3 = (const float*)d_in[5];
  const float* b3 = (const float*)d_in[6];
  const float* W4 = (const float*)d_in[7];
  const float* b4 = (const float*)d_in[8];
  const float* cb = (const float*)d_in[9];
  float* out = (float*)d_out;

  char* ws = (char*)d_ws;
  float*    sse    = (float*)(ws + 0);
  unsigned* hist   = (unsigned*)(ws + 1024);
  float*    cbnorm = (float*)(ws + 4096);
  bf16*     cbbf   = (bf16*)(ws + 8192);
  size_t off = 131072;
  bf16* xbf  = (bf16*)(ws + off);  off += (size_t)NB * NF * 2;
  bf16* wbuf = (bf16*)(ws + off);  off += (size_t)NB * NF * 2;
  bf16* hbf  = (bf16*)(ws + off);  off += (size_t)NB * NF * 2;
  float* latent = (float*)(ws + off); off += (size_t)NB * NF * 4;
  bf16* qbf  = xbf;   // alias: x dead after GEMM1
  bf16* h2bf = hbf;   // alias: h dead after GEMM2

  hipMemsetAsync(ws, 0, 3072, stream);  // sse + hist

  const int n8 = NB * NF / 8;
  cvt_f32_bf16<<<dim3(2048), dim3(256), 0, stream>>>(x,  xbf,  n8);
  cvt_f32_bf16<<<dim3(2048), dim3(256), 0, stream>>>(W1, wbuf, n8);
  cbprep<<<dim3(2), dim3(256), 0, stream>>>(cb, cbbf, cbnorm);

  dim3 ggrid(256), gblock(512);
  // h = relu(x @ W1^T + b1) -> bf16
  gemm256<1, 1><<<ggrid, gblock, 0, stream>>>(xbf, wbuf, b1, (float*)nullptr, hbf);
  cvt_f32_bf16<<<dim3(2048), dim3(256), 0, stream>>>(W2, wbuf, n8);
  // latent = h @ W2^T + b2 -> f32
  gemm256<0, 0><<<ggrid, gblock, 0, stream>>>(hbf, wbuf, b2, latent, (bf16*)nullptr);
  // VQ
  vq_kernel<<<dim3(512), dim3(512), 0, stream>>>(latent, cb, cbbf, cbnorm, qbf, hist, sse);
  cvt_f32_bf16<<<dim3(2048), dim3(256), 0, stream>>>(W3, wbuf, n8);
  // h2 = relu(q @ W3^T + b3) -> bf16
  gemm256<1, 1><<<ggrid, gblock, 0, stream>>>(qbf, wbuf, b3, (float*)nullptr, h2bf);
  cvt_f32_bf16<<<dim3(2048), dim3(256), 0, stream>>>(W4, wbuf, n8);
  // recons = h2 @ W4^T + b4 -> f32 (d_out)
  gemm256<0, 0><<<ggrid, gblock, 0, stream>>>(h2bf, wbuf, b4, out, (bf16*)nullptr);

  finalize_k<<<dim3(1), dim3(512), 0, stream>>>(hist, sse, out + (size_t)NB * NF);
}